// Round 2
// baseline (410.442 us; speedup 1.0000x reference)
//
#include <hip/hip_runtime.h>
#include <math.h>

#define BATCH 16
#define NCLS 80
#define NANCH 3
#define SUMHW 7581            // 76*76 + 38*38 + 19*19
#define NN (3 * SUMHW)        // 22743 boxes per image
#define TOPK 128
#define CAP 1024
#define CAPC 10240            // per-(b,c) candidate list capacity (mean ~7580, +37 sigma)

// exact sigmoid matching numpy f32 chain: correctly-rounded exp (double) -> f32 ops
__device__ __forceinline__ float sigf(float x) {
    float e = (float)exp(-(double)x);
    return 1.0f / (1.0f + e);
}
__device__ __forceinline__ float expf_cr(float x) {
    return (float)exp((double)x);
}

struct DecParams { float aw[9]; float ah[9]; };

// ---------------- Stage 1: decode + threshold compaction ----------------
// grid: 16 b * 3 a * 31 segs (23 s0 + 6 s1 + 2 s2) = 1488 blocks of 256
__global__ __launch_bounds__(256) void decode_kernel(
        const float* __restrict__ p0, const float* __restrict__ p1,
        const float* __restrict__ p2,
        float4* __restrict__ boxes, unsigned long long* __restrict__ cand,
        unsigned int* __restrict__ cnt, DecParams dp) {
    int blk = blockIdx.x;
    int b = blk / 93;
    int rem = blk % 93;
    int a = rem / 31;
    int seg = rem % 31;
    int s, cellblk;
    if (seg < 23)      { s = 0; cellblk = seg; }
    else if (seg < 29) { s = 1; cellblk = seg - 23; }
    else               { s = 2; cellblk = seg - 29; }
    const int SS_[3]  = {76, 38, 19};
    const int HW_[3]  = {5776, 1444, 361};
    const int OFF_[3] = {0, 5776, 7220};
    const float* __restrict__ pr = (s == 0) ? p0 : (s == 1) ? p1 : p2;
    int S = SS_[s], HW = HW_[s];
    int tid = threadIdx.x;
    int cell = cellblk * 256 + tid;
    bool valid = cell < HW;
    int cr = valid ? cell : (HW - 1);
    const float* pb = pr + ((size_t)b * 255 + (size_t)a * 85) * (size_t)HW + cr;

    float tx  = pb[0];
    float ty  = pb[(size_t)HW];
    float tw  = pb[(size_t)2 * HW];
    float th  = pb[(size_t)3 * HW];
    float obj = pb[(size_t)4 * HW];

    float Sf = (float)S;
    float gx = (float)(cr % S);
    float gy = (float)(cr / S);
    float cx = (sigf(tx) + gx) / Sf;
    float cy = (sigf(ty) + gy) / Sf;
    float aw = dp.aw[s * 3 + a], ah = dp.ah[s * 3 + a];
    float bw = expf_cr(tw) * aw;
    float bh = expf_cr(th) * ah;
    float x1 = cx - 0.5f * bw;
    float y1 = cy - 0.5f * bh;
    int n = a * SUMHW + OFF_[s] + cell;
    if (valid) boxes[(size_t)b * NN + n] = make_float4(x1, y1, x1 + bw, y1 + bh);

    float so = sigf(obj);
    // sc = fl(so * sig) <= so, so so<=0.3f implies sc<=0.3f: skip cell exactly.
    bool act = valid && (so > 0.3f);
    int rowb = b * NCLS;
    int lane = tid & 63;

    for (int c = 0; c < NCLS; ++c) {
        float x = pb[(size_t)(5 + c) * HW];   // coalesced per-class channel read
        bool push = false;
        float sc = 0.0f;
        if (act) {
            // fast prefilter (margin 1e-4 >> fast-exp error ~3e-7): never drops a true pass
            float st = 1.0f / (1.0f + __expf(-x));
            if (st * so > 0.2999f) {
                sc = so * sigf(x);            // exact chain, identical to reference
                push = sc > 0.3f;
            }
        }
        unsigned long long m = __ballot(push);
        if (m) {
            int leader = __ffsll(m) - 1;
            unsigned base = 0;
            if (lane == leader) base = atomicAdd(&cnt[rowb + c], (unsigned)__popcll(m));
            base = (unsigned)__shfl((int)base, leader);
            if (push) {
                unsigned rank = (unsigned)__popcll(m & ((1ULL << lane) - 1ULL));
                unsigned pos = base + rank;
                if (pos < CAPC)
                    cand[(size_t)(rowb + c) * CAPC + pos] =
                        ((unsigned long long)__float_as_uint(sc) << 32) |
                        (unsigned)(~(unsigned)n);
            }
        }
    }
}

// ---------------- Stage 2: per-(b,c) top-K select + greedy NMS ----------------
__global__ __launch_bounds__(256) void select_nms_kernel(
        const unsigned long long* __restrict__ cand,
        const unsigned int* __restrict__ cnt,
        const float4* __restrict__ boxes,
        float* __restrict__ out) {
    __shared__ unsigned long long sbuf[2048];   // 16KB: hist4[4][512] / hist2[4096] / skey[1024]
    __shared__ unsigned int sums[256];
    __shared__ float bxs[TOPK][4];
    __shared__ float areas[TOPK];
    __shared__ float pvs[TOPK];
    __shared__ unsigned int sh_bin, sh_above, gcount;

    int t = threadIdx.x;
    int bid = blockIdx.x;          // b*80 + c
    int b = bid / NCLS;
    int c = bid % NCLS;
    const unsigned long long* list = cand + (size_t)bid * CAPC;
    unsigned G = cnt[bid]; if (G > CAPC) G = CAPC;
    const float4* brow = boxes + (size_t)b * NN;

    unsigned prefix = 0;
    if (G > CAP) {
        // --- 512-bin histogram over key32, 4 per-wave copies ---
        unsigned int* h4 = (unsigned int*)sbuf;
        for (int i = t; i < 2048; i += 256) h4[i] = 0;
        __syncthreads();
        int w = t >> 6;
        for (unsigned i = t; i < G; i += 256) {
            unsigned key = (unsigned)(list[i] >> 32);
            atomicAdd(&h4[w * 512 + ((key - 0x3E800000u) >> 15)], 1u);
        }
        __syncthreads();
        unsigned m0 = h4[2*t] + h4[512+2*t] + h4[1024+2*t] + h4[1536+2*t];
        unsigned m1 = h4[2*t+1] + h4[512+2*t+1] + h4[1024+2*t+1] + h4[1536+2*t+1];
        sums[t] = m0 + m1;
        __syncthreads();
        for (int d = 1; d < 256; d <<= 1) {
            unsigned v = sums[t];
            if (t + d < 256) v += sums[t + d];
            __syncthreads();
            sums[t] = v;
            __syncthreads();
        }
        unsigned suf_incl = sums[t], suf_excl = suf_incl - (m0 + m1);
        if (suf_excl < TOPK && TOPK <= suf_incl) {     // unique crossing thread
            if (TOPK <= suf_excl + m1) { sh_bin = 2*t+1; sh_above = suf_excl; }
            else                       { sh_bin = 2*t;   sh_above = suf_excl + m1; }
        }
        __syncthreads();
        unsigned B1 = sh_bin, above1 = sh_above;
        unsigned cnt1 = h4[B1] + h4[512+B1] + h4[1024+B1] + h4[1536+B1];
        __syncthreads();   // h4 reads done before sbuf reuse

        if (above1 + cnt1 <= CAP) {
            prefix = 0x3E800000u + (B1 << 15);
        } else {
            // --- rare refine: bits [14:3] within bin B1 ---
            unsigned int* h2 = (unsigned int*)sbuf;
            for (int i = t; i < 4096; i += 256) h2[i] = 0;
            __syncthreads();
            for (unsigned i = t; i < G; i += 256) {
                unsigned key = (unsigned)(list[i] >> 32);
                if (((key - 0x3E800000u) >> 15) == B1)
                    atomicAdd(&h2[(key >> 3) & 0xFFFu], 1u);
            }
            __syncthreads();
            unsigned R2 = TOPK - above1;
            unsigned sl = 0;
#pragma unroll
            for (int k = 0; k < 16; ++k) sl += h2[t * 16 + k];
            sums[t] = sl;
            __syncthreads();
            for (int d = 1; d < 256; d <<= 1) {
                unsigned v = sums[t];
                if (t + d < 256) v += sums[t + d];
                __syncthreads();
                sums[t] = v;
                __syncthreads();
            }
            unsigned si = sums[t], se = si - sl;
            if (se < R2 && R2 <= si) {
                unsigned acc = se;
                for (int k = 15; k >= 0; --k) {
                    unsigned h = h2[t * 16 + k];
                    if (acc < R2 && R2 <= acc + h) { sh_bin = (unsigned)(t*16+k); break; }
                    acc += h;
                }
            }
            __syncthreads();
            prefix = 0x3E800000u + (B1 << 15) + (sh_bin << 3);
        }
    }

    // --- gather into skey ---
    unsigned long long* skey = sbuf;
    if (t == 0) gcount = 0;
    __syncthreads();
    if (G <= CAP) {
        for (unsigned i = t; i < G; i += 256) skey[i] = list[i];
    } else {
        for (unsigned i = t; i < G; i += 256) {
            unsigned long long e = list[i];
            if ((unsigned)(e >> 32) >= prefix) {
                unsigned pos = atomicAdd(&gcount, 1u);
                if (pos < CAP) skey[pos] = e;
            }
        }
    }
    __syncthreads();
    unsigned Gc = (G <= CAP) ? G : (gcount < CAP ? gcount : CAP);

    // --- bitonic sort descending on (score_bits, ~idx) ---
    int M = TOPK;
    while ((unsigned)M < Gc) M <<= 1;
    for (int i = t; i < M; i += 256) if ((unsigned)i >= Gc) skey[i] = 0ULL;
    __syncthreads();
    for (int k = 2; k <= M; k <<= 1) {
        for (int j = k >> 1; j > 0; j >>= 1) {
            for (int i = t; i < M; i += 256) {
                int l = i ^ j;
                if (l > i) {
                    unsigned long long a0 = skey[i], a1 = skey[l];
                    bool sw = ((i & k) == 0) ? (a0 < a1) : (a0 > a1);
                    if (sw) { skey[i] = a1; skey[l] = a0; }
                }
            }
            __syncthreads();
        }
    }

    // --- extract top-128 ---
    if (t < TOPK) {
        bool vld = (unsigned)t < Gc;
        unsigned long long e = vld ? skey[t] : 0ULL;
        float sc = __uint_as_float((unsigned)(e >> 32));
        unsigned n = ~(unsigned)(e & 0xFFFFFFFFu);
        float4 bb = make_float4(0.f, 0.f, 0.f, 0.f);
        if (vld) bb = brow[n];
        bxs[t][0] = bb.x; bxs[t][1] = bb.y; bxs[t][2] = bb.z; bxs[t][3] = bb.w;
        areas[t] = (bb.z - bb.x) * (bb.w - bb.y);
        pvs[t] = vld ? sc : -1.0f;
    }
    __syncthreads();

    // --- greedy NMS: wave-synchronous, zero barriers in the loop ---
    if (t < 64) {
        float p0v = pvs[t],      p1v = pvs[t + 64];
        float x10 = bxs[t][0],      y10 = bxs[t][1],      x20 = bxs[t][2],      y20 = bxs[t][3];
        float x11 = bxs[t+64][0],   y11 = bxs[t+64][1],   x21 = bxs[t+64][2],   y21 = bxs[t+64][3];
        float a0 = areas[t], a1 = areas[t + 64];
        for (int i = 0; i < TOPK; ++i) {
            bool hi = i >= 64; int src = i & 63;
            float pi = __shfl(hi ? p1v : p0v, src);
            if (pi > 0.0f) {                       // wave-uniform
                float xi1 = __shfl(hi ? x11 : x10, src);
                float yi1 = __shfl(hi ? y11 : y10, src);
                float xi2 = __shfl(hi ? x21 : x20, src);
                float yi2 = __shfl(hi ? y21 : y20, src);
                float ai  = __shfl(hi ? a1  : a0,  src);
                if (t > i) {
                    float xx1 = fmaxf(xi1, x10), yy1 = fmaxf(yi1, y10);
                    float xx2 = fminf(xi2, x20), yy2 = fminf(yi2, y20);
                    float ww = fmaxf(xx2 - xx1, 0.0f), hh = fmaxf(yy2 - yy1, 0.0f);
                    float inter = ww * hh;
                    float iou = inter / (ai + a0 - inter);
                    if (iou > 0.45f) p0v = -1.0f;
                }
                if (t + 64 > i) {
                    float xx1 = fmaxf(xi1, x11), yy1 = fmaxf(yi1, y11);
                    float xx2 = fminf(xi2, x21), yy2 = fminf(yi2, y21);
                    float ww = fmaxf(xx2 - xx1, 0.0f), hh = fmaxf(yy2 - yy1, 0.0f);
                    float inter = ww * hh;
                    float iou = inter / (ai + a1 - inter);
                    if (iou > 0.45f) p1v = -1.0f;
                }
            }
        }
        pvs[t] = p0v; pvs[t + 64] = p1v;
    }
    __syncthreads();

    // --- write [K,6] ---
    float* o = out + (size_t)bid * TOPK * 6;
    for (int i = t; i < TOPK; i += 256) {
        bool kept = pvs[i] > 0.0f;
        o[i * 6 + 0] = kept ? bxs[i][0] : 0.0f;
        o[i * 6 + 1] = kept ? bxs[i][1] : 0.0f;
        o[i * 6 + 2] = kept ? bxs[i][2] : 0.0f;
        o[i * 6 + 3] = kept ? bxs[i][3] : 0.0f;
        o[i * 6 + 4] = kept ? pvs[i] : 0.0f;
        o[i * 6 + 5] = (float)c;
    }
}

extern "C" void kernel_launch(void* const* d_in, const int* in_sizes, int n_in,
                              void* d_out, int out_size, void* d_ws, size_t ws_size,
                              hipStream_t stream) {
    const float* p0 = (const float*)d_in[0];
    const float* p1 = (const float*)d_in[1];
    const float* p2 = (const float*)d_in[2];
    float* out = (float*)d_out;

    char* ws = (char*)d_ws;
    unsigned int* cnt = (unsigned int*)ws;                         // 5120 B (pad 8192)
    float4* boxes = (float4*)(ws + 8192);                          // 5,822,208 B
    unsigned long long* cand =
        (unsigned long long*)(ws + 8192 + (size_t)BATCH * NN * 16); // 104,857,600 B

    static const float ANC[3][3][2] = {
        {{12, 16}, {19, 36}, {40, 28}},
        {{36, 75}, {76, 55}, {72, 146}},
        {{142, 110}, {192, 243}, {459, 401}},
    };
    static const int RED[3] = {8, 16, 32};
    static const int SS[3]  = {76, 38, 19};

    DecParams dp;
    for (int s = 0; s < 3; ++s)
        for (int a = 0; a < 3; ++a) {
            float Sf = (float)SS[s];
            dp.aw[s * 3 + a] = (ANC[s][a][0] / (float)RED[s]) / Sf;  // same f32 chain as ref
            dp.ah[s * 3 + a] = (ANC[s][a][1] / (float)RED[s]) / Sf;
        }

    hipMemsetAsync(cnt, 0, BATCH * NCLS * sizeof(unsigned int), stream);
    decode_kernel<<<BATCH * 93, 256, 0, stream>>>(p0, p1, p2, boxes, cand, cnt, dp);
    select_nms_kernel<<<BATCH * NCLS, 256, 0, stream>>>(cand, cnt, boxes, out);
}

// Round 3
// 188.356 us; speedup vs baseline: 2.1791x; 2.1791x over previous
//
#include <hip/hip_runtime.h>
#include <math.h>

#define BATCH 16
#define NCLS 80
#define SUMHW 7581            // 76*76 + 38*38 + 19*19
#define NN 22743              // 3 anchors * SUMHW
#define TOPK 128
#define CAP 1024
#define KEYBASE 0x3E800000u   // bits of 0.25f

// exact sigmoid matching numpy f32 chain: correctly-rounded exp (double) -> f32 ops
__device__ __forceinline__ float sigf(float x) {
    float e = (float)exp(-(double)x);
    return 1.0f / (1.0f + e);
}
__device__ __forceinline__ float expf_cr(float x) {
    return (float)exp((double)x);
}

struct DecParams { float aw[9]; float ah[9]; };

// ---------------- Stage A: decode boxes + exact objectness ----------------
// grid: 16 b * 3 a * 31 segs (23 s0 + 6 s1 + 2 s2) = 1488 blocks of 256
__global__ __launch_bounds__(256) void decode_kernel(
        const float* __restrict__ p0, const float* __restrict__ p1,
        const float* __restrict__ p2,
        float4* __restrict__ boxes, float* __restrict__ so_arr, DecParams dp) {
    int blk = blockIdx.x;
    int b = blk / 93;
    int rem = blk % 93;
    int a = rem / 31;
    int seg = rem % 31;
    int s, cellblk;
    if (seg < 23)      { s = 0; cellblk = seg; }
    else if (seg < 29) { s = 1; cellblk = seg - 23; }
    else               { s = 2; cellblk = seg - 29; }
    const int SS_[3]  = {76, 38, 19};
    const int HW_[3]  = {5776, 1444, 361};
    const int OFF_[3] = {0, 5776, 7220};
    const float* __restrict__ pr = (s == 0) ? p0 : (s == 1) ? p1 : p2;
    int S = SS_[s], HW = HW_[s];
    int cell = cellblk * 256 + (int)threadIdx.x;
    if (cell >= HW) return;
    const float* pb = pr + ((size_t)b * 255 + (size_t)a * 85) * (size_t)HW + cell;

    float tx  = pb[0];
    float ty  = pb[(size_t)HW];
    float tw  = pb[(size_t)2 * HW];
    float th  = pb[(size_t)3 * HW];
    float obj = pb[(size_t)4 * HW];

    float Sf = (float)S;
    float gx = (float)(cell % S);
    float gy = (float)(cell / S);
    float cx = (sigf(tx) + gx) / Sf;
    float cy = (sigf(ty) + gy) / Sf;
    float aw = dp.aw[s * 3 + a], ah = dp.ah[s * 3 + a];
    float bw = expf_cr(tw) * aw;
    float bh = expf_cr(th) * ah;
    float x1 = cx - 0.5f * bw;
    float y1 = cy - 0.5f * bh;
    int n = a * SUMHW + OFF_[s] + cell;
    boxes[(size_t)b * NN + n] = make_float4(x1, y1, x1 + bw, y1 + bh);
    so_arr[(size_t)b * NN + n] = sigf(obj);
}

// ------- Stage B: fused score + top-K select + greedy NMS, one block per (b,c) -------
__global__ __launch_bounds__(256) void select_nms_kernel(
        const float* __restrict__ p0, const float* __restrict__ p1,
        const float* __restrict__ p2,
        const float* __restrict__ so_arr,
        const float4* __restrict__ boxes,
        float* __restrict__ out) {
    __shared__ unsigned int hist[512];
    __shared__ unsigned int sums[256];
    __shared__ unsigned long long skey[CAP];
    __shared__ float bxs[TOPK][4];
    __shared__ float areas[TOPK];
    __shared__ float pvs[TOPK];
    __shared__ unsigned int sh_bin, sh_above, gcount;

    int t = threadIdx.x;
    int bid = blockIdx.x;          // b*80 + c
    int b = bid / NCLS;
    int c = bid % NCLS;
    const float4* brow = boxes + (size_t)b * NN;

    const int HW_[3]  = {5776, 1444, 361};
    const int OFF_[3] = {0, 5776, 7220};

    // generic scan over the 9 (scale, anchor) class-channel strips
    auto scan = [&](auto&& body) {
#pragma unroll
        for (int s = 0; s < 3; ++s) {
            const float* __restrict__ pr = (s == 0) ? p0 : (s == 1) ? p1 : p2;
            int HW = HW_[s];
#pragma unroll
            for (int a = 0; a < 3; ++a) {
                const float* __restrict__ cp =
                    pr + ((size_t)b * 255 + (size_t)a * 85 + 5 + (size_t)c) * (size_t)HW;
                int nb = a * SUMHW + OFF_[s];
                const float* __restrict__ sr = so_arr + (size_t)b * NN + nb;
                for (int i = t; i < HW; i += 256) {
                    float so = sr[i];
                    if (so <= 0.2999f) continue;      // approx <= so, so never a candidate
                    float x = cp[i];
                    float st = 1.0f / (1.0f + __expf(-x));   // approx sigmoid, err ~few ulp
                    float sca = st * so;
                    if (sca > 0.2999f) body(sca, x, so, nb + i);
                }
            }
        }
    };

    // --- pass 1: 512-bin histogram of approximate keys ---
    for (int i = t; i < 512; i += 256) hist[i] = 0;
    __syncthreads();
    scan([&](float sca, float, float, int) {
        unsigned bin = (__float_as_uint(sca) - KEYBASE) >> 15;
        if (bin > 511) bin = 511;
        atomicAdd(&hist[bin], 1u);
    });
    __syncthreads();

    // suffix scan (2 bins per thread, high bin = high score)
    unsigned m0 = hist[2 * t], m1 = hist[2 * t + 1];
    sums[t] = m0 + m1;
    __syncthreads();
    for (int d = 1; d < 256; d <<= 1) {
        unsigned v = sums[t];
        if (t + d < 256) v += sums[t + d];
        __syncthreads();
        sums[t] = v;
        __syncthreads();
    }
    unsigned total = sums[0];
    bool gatherAll = (total < TOPK);
    unsigned gth = 0;
    if (!gatherAll) {
        unsigned suf_incl = sums[t], suf_excl = suf_incl - (m0 + m1);
        if (suf_excl < TOPK && TOPK <= suf_incl) {          // unique crossing thread
            if (TOPK <= suf_excl + m1) { sh_bin = 2 * t + 1; sh_above = suf_excl; }
            else                       { sh_bin = 2 * t;     sh_above = suf_excl + m1; }
        }
        __syncthreads();
        unsigned B1 = sh_bin, above1 = sh_above;
        unsigned cntB = hist[B1];
        unsigned binlo = KEYBASE + (B1 << 15);
        if (above1 + cntB <= 768) {
            gth = binlo - 256;              // 256-ulp margin >> approx error (~7 ulp)
        } else {
            // --- rare refine: 256 sub-bins of 128 ulp within bin B1 ---
            __syncthreads();                // everyone done reading hist
            hist[t] = 0; if (t + 256 < 512) hist[t + 256] = 0;
            __syncthreads();
            scan([&](float sca, float, float, int) {
                unsigned key = __float_as_uint(sca);
                if (((key - KEYBASE) >> 15) == B1) {
                    unsigned sub = (key - binlo) >> 7;
                    if (sub > 255) sub = 255;
                    atomicAdd(&hist[sub], 1u);
                }
            });
            __syncthreads();
            unsigned R2 = TOPK - above1;
            unsigned sl = hist[t];
            sums[t] = sl;
            __syncthreads();
            for (int d = 1; d < 256; d <<= 1) {
                unsigned v = sums[t];
                if (t + d < 256) v += sums[t + d];
                __syncthreads();
                sums[t] = v;
                __syncthreads();
            }
            unsigned si = sums[t], se = si - sl;
            if (se < R2 && R2 <= si) sh_bin = (unsigned)t;
            __syncthreads();
            gth = binlo + (sh_bin << 7) - 256;
        }
    } else {
        __syncthreads();
    }

    // --- pass 2: gather survivors; exact score only for them ---
    if (t == 0) gcount = 0;
    __syncthreads();
    scan([&](float sca, float x, float so, int n) {
        unsigned key = __float_as_uint(sca);
        if (gatherAll || key >= gth) {
            unsigned pos = atomicAdd(&gcount, 1u);
            if (pos < CAP) {
                float ex = so * sigf(x);      // exact chain, identical to reference
                skey[pos] = (ex > 0.3f)
                    ? (((unsigned long long)__float_as_uint(ex) << 32) |
                       (unsigned)(~(unsigned)n))
                    : 0ULL;
            }
        }
    });
    __syncthreads();
    unsigned Gc = gcount < CAP ? gcount : CAP;

    // --- bitonic sort descending on (score_bits, ~idx) ---
    int M = TOPK;
    while ((unsigned)M < Gc) M <<= 1;
    for (int i = t; i < M; i += 256) if ((unsigned)i >= Gc) skey[i] = 0ULL;
    __syncthreads();
    for (int k = 2; k <= M; k <<= 1) {
        for (int j = k >> 1; j > 0; j >>= 1) {
            for (int i = t; i < M; i += 256) {
                int l = i ^ j;
                if (l > i) {
                    unsigned long long a0 = skey[i], a1 = skey[l];
                    bool sw = ((i & k) == 0) ? (a0 < a1) : (a0 > a1);
                    if (sw) { skey[i] = a1; skey[l] = a0; }
                }
            }
            __syncthreads();
        }
    }

    // --- extract top-128 ---
    if (t < TOPK) {
        bool vld = ((unsigned)t < Gc) && (skey[t] != 0ULL);
        unsigned long long e = vld ? skey[t] : 0ULL;
        float sc = __uint_as_float((unsigned)(e >> 32));
        unsigned n = ~(unsigned)(e & 0xFFFFFFFFu);
        float4 bb = make_float4(0.f, 0.f, 0.f, 0.f);
        if (vld) bb = brow[n];
        bxs[t][0] = bb.x; bxs[t][1] = bb.y; bxs[t][2] = bb.z; bxs[t][3] = bb.w;
        areas[t] = (bb.z - bb.x) * (bb.w - bb.y);
        pvs[t] = vld ? sc : -1.0f;
    }
    __syncthreads();

    // --- greedy NMS: wave-synchronous, zero barriers in the loop ---
    if (t < 64) {
        float pv0 = pvs[t],        pv1 = pvs[t + 64];
        float x10 = bxs[t][0],     y10 = bxs[t][1],     x20 = bxs[t][2],     y20 = bxs[t][3];
        float x11 = bxs[t+64][0],  y11 = bxs[t+64][1],  x21 = bxs[t+64][2],  y21 = bxs[t+64][3];
        float a0 = areas[t], a1 = areas[t + 64];
        for (int i = 0; i < TOPK; ++i) {
            bool hi = i >= 64; int src = i & 63;
            float pi = __shfl(hi ? pv1 : pv0, src);
            if (pi > 0.0f) {                       // wave-uniform
                float xi1 = __shfl(hi ? x11 : x10, src);
                float yi1 = __shfl(hi ? y11 : y10, src);
                float xi2 = __shfl(hi ? x21 : x20, src);
                float yi2 = __shfl(hi ? y21 : y20, src);
                float ai  = __shfl(hi ? a1  : a0,  src);
                if (t > i) {
                    float xx1 = fmaxf(xi1, x10), yy1 = fmaxf(yi1, y10);
                    float xx2 = fminf(xi2, x20), yy2 = fminf(yi2, y20);
                    float ww = fmaxf(xx2 - xx1, 0.0f), hh = fmaxf(yy2 - yy1, 0.0f);
                    float inter = ww * hh;
                    float iou = inter / (ai + a0 - inter);
                    if (iou > 0.45f) pv0 = -1.0f;
                }
                if (t + 64 > i) {
                    float xx1 = fmaxf(xi1, x11), yy1 = fmaxf(yi1, y11);
                    float xx2 = fminf(xi2, x21), yy2 = fminf(yi2, y21);
                    float ww = fmaxf(xx2 - xx1, 0.0f), hh = fmaxf(yy2 - yy1, 0.0f);
                    float inter = ww * hh;
                    float iou = inter / (ai + a1 - inter);
                    if (iou > 0.45f) pv1 = -1.0f;
                }
            }
        }
        pvs[t] = pv0; pvs[t + 64] = pv1;
    }
    __syncthreads();

    // --- write [K,6] = x1,y1,x2,y2,score,class ---
    float* o = out + (size_t)bid * TOPK * 6;
    for (int i = t; i < TOPK; i += 256) {
        bool kept = pvs[i] > 0.0f;
        o[i * 6 + 0] = kept ? bxs[i][0] : 0.0f;
        o[i * 6 + 1] = kept ? bxs[i][1] : 0.0f;
        o[i * 6 + 2] = kept ? bxs[i][2] : 0.0f;
        o[i * 6 + 3] = kept ? bxs[i][3] : 0.0f;
        o[i * 6 + 4] = kept ? pvs[i] : 0.0f;
        o[i * 6 + 5] = (float)c;
    }
}

extern "C" void kernel_launch(void* const* d_in, const int* in_sizes, int n_in,
                              void* d_out, int out_size, void* d_ws, size_t ws_size,
                              hipStream_t stream) {
    const float* p0 = (const float*)d_in[0];
    const float* p1 = (const float*)d_in[1];
    const float* p2 = (const float*)d_in[2];
    float* out = (float*)d_out;

    char* ws = (char*)d_ws;
    float4* boxes = (float4*)ws;                                   // 5,822,208 B
    float*  so_arr = (float*)(ws + (size_t)BATCH * NN * 16);       // 1,455,552 B

    static const float ANC[3][3][2] = {
        {{12, 16}, {19, 36}, {40, 28}},
        {{36, 75}, {76, 55}, {72, 146}},
        {{142, 110}, {192, 243}, {459, 401}},
    };
    static const int RED[3] = {8, 16, 32};
    static const int SS[3]  = {76, 38, 19};

    DecParams dp;
    for (int s = 0; s < 3; ++s)
        for (int a = 0; a < 3; ++a) {
            float Sf = (float)SS[s];
            dp.aw[s * 3 + a] = (ANC[s][a][0] / (float)RED[s]) / Sf;  // same f32 chain as ref
            dp.ah[s * 3 + a] = (ANC[s][a][1] / (float)RED[s]) / Sf;
        }

    decode_kernel<<<BATCH * 93, 256, 0, stream>>>(p0, p1, p2, boxes, so_arr, dp);
    select_nms_kernel<<<BATCH * NCLS, 256, 0, stream>>>(p0, p1, p2, so_arr, boxes, out);
}

// Round 4
// 98.703 us; speedup vs baseline: 4.1583x; 1.9083x over previous
//
#include <hip/hip_runtime.h>
#include <math.h>

#define BATCH 16
#define NCLS 80
#define SUMHW 7581            // 76*76 + 38*38 + 19*19
#define NN 22743              // 3 anchors * SUMHW
#define ASTRIDE 7584          // padded per-anchor stride for so_arr (7581 -> 7584, /4)
#define PADNN (3 * ASTRIDE)   // 22752
#define TOPK 128
#define CAP 1024
#define BUFCAP 1536
#define KEYBASE 0x3E800000u   // bits of 0.25f
#define SBITS   0x3F19999Au   // bits of 0.6f  (static LDS-buffer push threshold)

// exact sigmoid matching numpy f32 chain: correctly-rounded exp (double) -> f32 ops
__device__ __forceinline__ float sigf(float x) {
    float e = (float)exp(-(double)x);
    return 1.0f / (1.0f + e);
}
__device__ __forceinline__ float expf_cr(float x) {
    return (float)exp((double)x);
}

struct DecParams { float aw[9]; float ah[9]; };

// ---------------- Stage A: decode boxes + exact objectness ----------------
__global__ __launch_bounds__(256) void decode_kernel(
        const float* __restrict__ p0, const float* __restrict__ p1,
        const float* __restrict__ p2,
        float4* __restrict__ boxes, float* __restrict__ so_arr, DecParams dp) {
    int blk = blockIdx.x;
    int b = blk / 93;
    int rem = blk % 93;
    int a = rem / 31;
    int seg = rem % 31;
    int s, cellblk;
    if (seg < 23)      { s = 0; cellblk = seg; }
    else if (seg < 29) { s = 1; cellblk = seg - 23; }
    else               { s = 2; cellblk = seg - 29; }
    const int SS_[3]  = {76, 38, 19};
    const int HW_[3]  = {5776, 1444, 361};
    const int OFF_[3] = {0, 5776, 7220};
    const float* __restrict__ pr = (s == 0) ? p0 : (s == 1) ? p1 : p2;
    int S = SS_[s], HW = HW_[s];
    int cell = cellblk * 256 + (int)threadIdx.x;
    if (cell >= HW) return;
    const float* pb = pr + ((size_t)b * 255 + (size_t)a * 85) * (size_t)HW + cell;

    float tx  = pb[0];
    float ty  = pb[(size_t)HW];
    float tw  = pb[(size_t)2 * HW];
    float th  = pb[(size_t)3 * HW];
    float obj = pb[(size_t)4 * HW];

    float Sf = (float)S;
    float gx = (float)(cell % S);
    float gy = (float)(cell / S);
    float cx = (sigf(tx) + gx) / Sf;
    float cy = (sigf(ty) + gy) / Sf;
    float aw = dp.aw[s * 3 + a], ah = dp.ah[s * 3 + a];
    float bw = expf_cr(tw) * aw;
    float bh = expf_cr(th) * ah;
    float x1 = cx - 0.5f * bw;
    float y1 = cy - 0.5f * bh;
    int n = a * SUMHW + OFF_[s] + cell;
    boxes[(size_t)b * NN + n] = make_float4(x1, y1, x1 + bw, y1 + bh);
    so_arr[(size_t)b * PADNN + a * ASTRIDE + OFF_[s] + cell] = sigf(obj);
}

// ------- Stage B: fused score + top-K select + greedy NMS, one block per (b,c) -------
__global__ __launch_bounds__(256) void select_nms_kernel(
        const float* __restrict__ p0, const float* __restrict__ p1,
        const float* __restrict__ p2,
        const float* __restrict__ so_arr,
        const float4* __restrict__ boxes,
        float* __restrict__ out) {
    __shared__ unsigned int hist[512];
    __shared__ unsigned int sums[256];
    __shared__ unsigned long long skey[CAP];
    __shared__ unsigned int bkey[BUFCAP];
    __shared__ unsigned int bidx[BUFCAP];
    __shared__ float bxs[TOPK][4];
    __shared__ float areas[TOPK];
    __shared__ float pvs[TOPK];
    __shared__ unsigned int sh_bin, sh_above, gcount, bufn;

    int t = threadIdx.x;
    int bid = blockIdx.x;          // b*80 + c
    int b = bid / NCLS;
    int c = bid % NCLS;
    const float4* brow = boxes + (size_t)b * NN;

    for (int i = t; i < 512; i += 256) hist[i] = 0;
    if (t == 0) { bufn = 0; gcount = 0; }
    __syncthreads();

    // --- single fused pass: approx-key histogram + static-threshold buffer push ---
    auto process = [&](float x, float so, int n) {
        float st = 1.0f / (1.0f + __expf(-x));   // approx sigmoid, err few ulp
        float sca = st * so;
        if (so > 0.2999f && sca > 0.2999f) {     // superset of exact >0.3 candidates
            unsigned key = __float_as_uint(sca);
            unsigned bin = (key - KEYBASE) >> 15; if (bin > 511u) bin = 511u;
            atomicAdd(&hist[bin], 1u);
            if (key >= SBITS) {
                unsigned p = atomicAdd(&bufn, 1u);
                if (p < BUFCAP) { bkey[p] = key; bidx[p] = (unsigned)n; }
            }
        }
    };

#pragma unroll
    for (int s = 0; s < 2; ++s) {               // s0/s1: HW % 4 == 0 -> aligned float4
        const float* __restrict__ pr = (s == 0) ? p0 : p1;
        const int HW  = (s == 0) ? 5776 : 1444;
        const int OFF = (s == 0) ? 0 : 5776;
#pragma unroll
        for (int a = 0; a < 3; ++a) {
            const float4* __restrict__ cp4 =
                (const float4*)(pr + ((size_t)b * 255 + (size_t)a * 85 + 5 + (size_t)c) * (size_t)HW);
            const float4* __restrict__ so4 =
                (const float4*)(so_arr + (size_t)b * PADNN + a * ASTRIDE + OFF);
            int n0 = a * SUMHW + OFF;
            int nq = HW >> 2;
            for (int i = t; i < nq; i += 256) {
                float4 xv = cp4[i];
                float4 sv = so4[i];
                int n = n0 + 4 * i;
                process(xv.x, sv.x, n);
                process(xv.y, sv.y, n + 1);
                process(xv.z, sv.z, n + 2);
                process(xv.w, sv.w, n + 3);
            }
        }
    }
#pragma unroll
    for (int a = 0; a < 3; ++a) {               // s2: HW=361, unaligned -> scalar
        const float* __restrict__ cp = p2 + ((size_t)b * 255 + (size_t)a * 85 + 5 + (size_t)c) * 361;
        const float* __restrict__ sop = so_arr + (size_t)b * PADNN + a * ASTRIDE + 7220;
        int n0 = a * SUMHW + 7220;
        for (int i = t; i < 361; i += 256) process(cp[i], sop[i], n0 + i);
    }
    __syncthreads();

    // --- suffix scan of histogram (2 bins/thread, high bin = high score) ---
    unsigned m0 = hist[2 * t], m1 = hist[2 * t + 1];
    sums[t] = m0 + m1;
    __syncthreads();
    for (int d = 1; d < 256; d <<= 1) {
        unsigned v = sums[t];
        if (t + d < 256) v += sums[t + d];
        __syncthreads();
        sums[t] = v;
        __syncthreads();
    }
    unsigned total = sums[0];
    bool gatherAll = (total < TOPK);
    bool scanGather = gatherAll;                 // fallback: global re-scan gather
    unsigned gth = 0;

    // scalar re-scan helper for the (rare) fallback paths
    auto scanScalar = [&](auto&& body) {
#pragma unroll
        for (int s = 0; s < 3; ++s) {
            const float* __restrict__ pr = (s == 0) ? p0 : (s == 1) ? p1 : p2;
            const int HW  = (s == 0) ? 5776 : (s == 1) ? 1444 : 361;
            const int OFF = (s == 0) ? 0 : (s == 1) ? 5776 : 7220;
#pragma unroll
            for (int a = 0; a < 3; ++a) {
                const float* __restrict__ cp =
                    pr + ((size_t)b * 255 + (size_t)a * 85 + 5 + (size_t)c) * (size_t)HW;
                const float* __restrict__ sop = so_arr + (size_t)b * PADNN + a * ASTRIDE + OFF;
                int n0 = a * SUMHW + OFF;
                for (int i = t; i < HW; i += 256) {
                    float so = sop[i];
                    if (so <= 0.2999f) continue;
                    float x = cp[i];
                    float st = 1.0f / (1.0f + __expf(-x));
                    float sca = st * so;
                    if (sca > 0.2999f) body(sca, x, so, n0 + i);
                }
            }
        }
    };

    if (!gatherAll) {
        unsigned suf_incl = sums[t], suf_excl = suf_incl - (m0 + m1);
        if (suf_excl < TOPK && TOPK <= suf_incl) {      // unique crossing thread
            if (TOPK <= suf_excl + m1) { sh_bin = 2 * t + 1; sh_above = suf_excl; }
            else                       { sh_bin = 2 * t;     sh_above = suf_excl + m1; }
        }
        __syncthreads();
        unsigned B1 = sh_bin, above1 = sh_above;
        unsigned cntB = hist[B1];
        unsigned binlo = KEYBASE + (B1 << 15);
        __syncthreads();

        if (above1 + cntB <= 768) {
            gth = binlo - 256;           // 256-ulp margin >> approx error (validated r3)
        } else {
            // --- rare refine: 256 sub-bins of 128 ulp within bin B1 (global re-scan) ---
            if (t < 256) hist[t] = 0;
            __syncthreads();
            scanScalar([&](float sca, float, float, int) {
                unsigned key = __float_as_uint(sca);
                if (((key - KEYBASE) >> 15) == B1) {
                    unsigned sub = (key - binlo) >> 7; if (sub > 255u) sub = 255u;
                    atomicAdd(&hist[sub], 1u);
                }
            });
            __syncthreads();
            unsigned R2 = TOPK - above1;
            unsigned sl = hist[t];
            sums[t] = sl;
            __syncthreads();
            for (int d = 1; d < 256; d <<= 1) {
                unsigned v = sums[t];
                if (t + d < 256) v += sums[t + d];
                __syncthreads();
                sums[t] = v;
                __syncthreads();
            }
            unsigned si = sums[t], se = si - sl;
            if (se < R2 && R2 <= si) sh_bin = (unsigned)t;
            __syncthreads();
            gth = binlo + (sh_bin << 7) - 256;
            scanGather = true;
        }
        if (!scanGather && (gth < SBITS || bufn > BUFCAP)) scanGather = true;
    } else {
        __syncthreads(); __syncthreads();
    }

    // --- gather survivors + exact rescore (reference-identical f32 chain) ---
    if (scanGather) {
        scanScalar([&](float sca, float x, float so, int n) {
            unsigned key = __float_as_uint(sca);
            if (gatherAll || key >= gth) {
                unsigned pos = atomicAdd(&gcount, 1u);
                if (pos < CAP) {
                    float ex = so * sigf(x);
                    skey[pos] = (ex > 0.3f)
                        ? (((unsigned long long)__float_as_uint(ex) << 32) |
                           (unsigned)(~(unsigned)n))
                        : 0ULL;
                }
            }
        });
    } else {
        unsigned bn = bufn;              // <= BUFCAP on this path
        for (unsigned i = t; i < bn; i += 256) {
            if (bkey[i] >= gth) {
                unsigned pos = atomicAdd(&gcount, 1u);
                if (pos < CAP) {
                    unsigned n = bidx[i];
                    unsigned a = n / SUMHW;
                    int r = (int)(n - a * SUMHW);
                    size_t chan = (size_t)b * 255 + (size_t)a * 85 + 5 + (size_t)c;
                    float x;
                    if (r < 5776)      x = p0[chan * 5776 + r];
                    else if (r < 7220) x = p1[chan * 1444 + (r - 5776)];
                    else               x = p2[chan * 361  + (r - 7220)];
                    float so = so_arr[(size_t)b * PADNN + a * ASTRIDE + r];
                    float ex = so * sigf(x);
                    skey[pos] = (ex > 0.3f)
                        ? (((unsigned long long)__float_as_uint(ex) << 32) |
                           (unsigned)(~n))
                        : 0ULL;
                }
            }
        }
    }
    __syncthreads();
    unsigned Gc = gcount < CAP ? gcount : CAP;

    // --- bitonic sort descending on (score_bits, ~idx) ---
    int M = TOPK;
    while ((unsigned)M < Gc) M <<= 1;
    for (int i = t; i < M; i += 256) if ((unsigned)i >= Gc) skey[i] = 0ULL;
    __syncthreads();
    for (int k = 2; k <= M; k <<= 1) {
        for (int j = k >> 1; j > 0; j >>= 1) {
            for (int i = t; i < M; i += 256) {
                int l = i ^ j;
                if (l > i) {
                    unsigned long long a0 = skey[i], a1 = skey[l];
                    bool sw = ((i & k) == 0) ? (a0 < a1) : (a0 > a1);
                    if (sw) { skey[i] = a1; skey[l] = a0; }
                }
            }
            __syncthreads();
        }
    }

    // --- extract top-128 ---
    if (t < TOPK) {
        bool vld = ((unsigned)t < Gc) && (skey[t] != 0ULL);
        unsigned long long e = vld ? skey[t] : 0ULL;
        float sc = __uint_as_float((unsigned)(e >> 32));
        unsigned n = ~(unsigned)(e & 0xFFFFFFFFu);
        float4 bb = make_float4(0.f, 0.f, 0.f, 0.f);
        if (vld) bb = brow[n];
        bxs[t][0] = bb.x; bxs[t][1] = bb.y; bxs[t][2] = bb.z; bxs[t][3] = bb.w;
        areas[t] = (bb.z - bb.x) * (bb.w - bb.y);
        pvs[t] = vld ? sc : -1.0f;
    }
    __syncthreads();

    // --- greedy NMS: wave-synchronous, zero barriers in the loop ---
    if (t < 64) {
        float pv0 = pvs[t],        pv1 = pvs[t + 64];
        float x10 = bxs[t][0],     y10 = bxs[t][1],     x20 = bxs[t][2],     y20 = bxs[t][3];
        float x11 = bxs[t+64][0],  y11 = bxs[t+64][1],  x21 = bxs[t+64][2],  y21 = bxs[t+64][3];
        float a0 = areas[t], a1 = areas[t + 64];
        for (int i = 0; i < TOPK; ++i) {
            bool hi = i >= 64; int src = i & 63;
            float pi = __shfl(hi ? pv1 : pv0, src);
            if (pi > 0.0f) {                       // wave-uniform
                float xi1 = __shfl(hi ? x11 : x10, src);
                float yi1 = __shfl(hi ? y11 : y10, src);
                float xi2 = __shfl(hi ? x21 : x20, src);
                float yi2 = __shfl(hi ? y21 : y20, src);
                float ai  = __shfl(hi ? a1  : a0,  src);
                if (t > i) {
                    float xx1 = fmaxf(xi1, x10), yy1 = fmaxf(yi1, y10);
                    float xx2 = fminf(xi2, x20), yy2 = fminf(yi2, y20);
                    float ww = fmaxf(xx2 - xx1, 0.0f), hh = fmaxf(yy2 - yy1, 0.0f);
                    float inter = ww * hh;
                    float iou = inter / (ai + a0 - inter);
                    if (iou > 0.45f) pv0 = -1.0f;
                }
                if (t + 64 > i) {
                    float xx1 = fmaxf(xi1, x11), yy1 = fmaxf(yi1, y11);
                    float xx2 = fminf(xi2, x21), yy2 = fminf(yi2, y21);
                    float ww = fmaxf(xx2 - xx1, 0.0f), hh = fmaxf(yy2 - yy1, 0.0f);
                    float inter = ww * hh;
                    float iou = inter / (ai + a1 - inter);
                    if (iou > 0.45f) pv1 = -1.0f;
                }
            }
        }
        pvs[t] = pv0; pvs[t + 64] = pv1;
    }
    __syncthreads();

    // --- write [K,6] = x1,y1,x2,y2,score,class ---
    float* o = out + (size_t)bid * TOPK * 6;
    for (int i = t; i < TOPK; i += 256) {
        bool kept = pvs[i] > 0.0f;
        o[i * 6 + 0] = kept ? bxs[i][0] : 0.0f;
        o[i * 6 + 1] = kept ? bxs[i][1] : 0.0f;
        o[i * 6 + 2] = kept ? bxs[i][2] : 0.0f;
        o[i * 6 + 3] = kept ? bxs[i][3] : 0.0f;
        o[i * 6 + 4] = kept ? pvs[i] : 0.0f;
        o[i * 6 + 5] = (float)c;
    }
}

extern "C" void kernel_launch(void* const* d_in, const int* in_sizes, int n_in,
                              void* d_out, int out_size, void* d_ws, size_t ws_size,
                              hipStream_t stream) {
    const float* p0 = (const float*)d_in[0];
    const float* p1 = (const float*)d_in[1];
    const float* p2 = (const float*)d_in[2];
    float* out = (float*)d_out;

    char* ws = (char*)d_ws;
    float4* boxes = (float4*)ws;                                   // 5,822,208 B
    float*  so_arr = (float*)(ws + (size_t)BATCH * NN * 16);       // 16*22752*4 = 1,456,128 B

    static const float ANC[3][3][2] = {
        {{12, 16}, {19, 36}, {40, 28}},
        {{36, 75}, {76, 55}, {72, 146}},
        {{142, 110}, {192, 243}, {459, 401}},
    };
    static const int RED[3] = {8, 16, 32};
    static const int SS[3]  = {76, 38, 19};

    DecParams dp;
    for (int s = 0; s < 3; ++s)
        for (int a = 0; a < 3; ++a) {
            float Sf = (float)SS[s];
            dp.aw[s * 3 + a] = (ANC[s][a][0] / (float)RED[s]) / Sf;  // same f32 chain as ref
            dp.ah[s * 3 + a] = (ANC[s][a][1] / (float)RED[s]) / Sf;
        }

    decode_kernel<<<BATCH * 93, 256, 0, stream>>>(p0, p1, p2, boxes, so_arr, dp);
    select_nms_kernel<<<BATCH * NCLS, 256, 0, stream>>>(p0, p1, p2, so_arr, boxes, out);
}